// Round 13
// baseline (2880.629 us; speedup 1.0000x reference)
//
#include <hip/hip_runtime.h>

#define NB 32
#define NP 65536
#define NS 1024
#define NT 1024
#define BPB 8                 // blocks per batch (proven best, R7)
#define CHUNK (NP / BPB)      // 8192 points per block
#define PPT (CHUNK / NT)      // 8 points per thread

typedef unsigned long long u64;
typedef unsigned int u32;
typedef int int4v __attribute__((ext_vector_type(4)));

// ---------------- R13: every-wave polling, ONE barrier per iteration --------
// Protocol = R7 verbatim (proven 2222us, absmax 0): per-s write-once 32B
// slots, h0={keylo,keyhi,x,y} h1={keylo,keyhi,z,0}, valid iff keylo!=0 &&
// h0.key==h1.key; stores/loads sc0 sc1 (bypass L1+L2 — R10/R11 lesson: an
// sc0-cached poll line is never invalidated by remote writes).
// Structural change: cand[] double-buffered by parity -> single __syncthreads
// per iteration; ALL 16 waves stage2-reduce + poll + compute q in registers
// (no LDS q-broadcast, no second barrier). Deadlock-safe: each block's slot
// store is wave0's straight-line code BEFORE wave0's polls (R8/R9 rule);
// other waves poll only FOREIGN slots, never their own block's.
__global__ __launch_bounds__(NT) void fps_v13(const float* __restrict__ pts,
                                              float* __restrict__ out,
                                              u32* __restrict__ slots) {
#pragma clang fp contract(off)
    const int bid = blockIdx.x;
    const int b = bid >> 3;           // batch: consecutive bids (R7 mapping)
    const int j = bid & 7;
    const int t = threadIdx.x;
    const int wave = t >> 6;
    const int lane = t & 63;
    const int base = j * CHUNK;
    const float* __restrict__ pb = pts + (size_t)b * NP * 3;
    float* __restrict__ out_idx = out + (size_t)b * NS;
    float* __restrict__ out_pts = out + (size_t)NB * NS + (size_t)b * NS * 3;
    u32* __restrict__ slot_b = slots + (size_t)b * NS * BPB * 8;  // u32 words

    __shared__ float P[CHUNK * 3];    // 96 KB packed points
    __shared__ u64 cand[2][NT / 64];  // parity double-buffer
    __shared__ int sel_hist[NS];

    // stage chunk into LDS, coalesced float4
    {
        const float4* __restrict__ src4 = (const float4*)(pb + (size_t)base * 3);
        float4* dst4 = (float4*)P;
#pragma unroll
        for (int k = 0; k < (CHUNK * 3 / 4) / NT; ++k) dst4[t + k * NT] = src4[t + k * NT];
    }
    if (t == 0) {
        sel_hist[0] = 0;
        if (j == 0) out_idx[0] = 0.0f;
    }
    __syncthreads();

    // points -> registers, CONSECUTIVE range [t*8, t*8+8):
    // lowest lane == lowest global idx (exact ballot tie-break, R10-R12)
    float px[PPT], py[PPT], pz[PPT], md[PPT];
#pragma unroll
    for (int i = 0; i < PPT; ++i) {
        const int li = t * PPT + i;
        px[i] = P[li * 3 + 0];
        py[i] = P[li * 3 + 1];
        pz[i] = P[li * 3 + 2];
        md[i] = 1e10f;
    }
    // first selected point = index 0 (one-time broadcast load)
    float qx = pb[0], qy = pb[1], qz = pb[2];

    for (int s = 1; s < NS; ++s) {
        const int par = s & 1;
        float bv = -1.0f;
        int bi = 0;
#pragma unroll
        for (int i = 0; i < PPT; ++i) {
            float dx = px[i] - qx;
            float dy = py[i] - qy;
            float dz = pz[i] - qz;
            float d = (dx * dx + dy * dy) + dz * dz;   // match np reduce order
            float nmd = fminf(md[i], d);
            md[i] = nmd;
            if (nmd > bv) { bv = nmd; bi = t * PPT + i; }  // strict >: min idx
        }
        // wave argmax: f32 max reduce; ballot lowest lane among ties == min idx
        float m = bv;
#pragma unroll
        for (int d1 = 32; d1 >= 1; d1 >>= 1) m = fmaxf(m, __shfl_xor(m, d1, 64));
        u64 msk = __ballot(bv == m);
        int src = __ffsll((unsigned long long)msk) - 1;
        int biw = __shfl(bi, src, 64);
        if (lane == 0)
            cand[par][wave] = ((u64)__float_as_uint(m) << 32) |
                              (u64)(0xFFFFFFFFu - (u32)(base + biw));
        __syncthreads();                   // the ONLY barrier per iteration
        // stage-2 (every wave): reduce the 16 wave candidates
        u64 c = cand[par][lane & 15];
#pragma unroll
        for (int d1 = 8; d1 >= 1; d1 >>= 1) {
            u64 o = __shfl_xor(c, d1, 64);
            c = (o > c) ? o : c;
        }
        // ---- writer: wave0 lane0, loop-free, completes before any poll ----
        if (wave == 0 && lane == 0) {
            const int lw = (int)(0xFFFFFFFFu - (u32)c) - base;
            int4v h0, h1;
            h0.x = (int)(u32)c;               // key lo = ~gidx (never 0)
            h0.y = (int)(u32)(c >> 32);       // key hi = valbits
            h0.z = __float_as_int(P[lw * 3 + 0]);
            h0.w = __float_as_int(P[lw * 3 + 1]);
            h1.x = h0.x;
            h1.y = h0.y;
            h1.z = __float_as_int(P[lw * 3 + 2]);
            h1.w = 0;
            u32* sp = slot_b + ((size_t)s * BPB + j) * 8;
            asm volatile(
                "global_store_dwordx4 %0, %2, off sc0 sc1\n\t"
                "global_store_dwordx4 %1, %3, off sc0 sc1"
                :: "v"(sp), "v"(sp + 4), "v"(h0), "v"(h1) : "memory");
        }
        // ---- pollers: EVERY wave, lanes 0-7 except own j ----
        u64 k = c;
        float wx = 0.f, wy = 0.f, wz = 0.f;
        if (lane < BPB && lane != j) {
            const u32* sp = slot_b + ((size_t)s * BPB + lane) * 8;
            int4v a, bb;
            for (;;) {
                asm volatile(
                    "global_load_dwordx4 %0, %2, off sc0 sc1\n\t"
                    "global_load_dwordx4 %1, %3, off sc0 sc1\n\t"
                    "s_waitcnt vmcnt(0)"
                    : "=&v"(a), "=&v"(bb)
                    : "v"(sp), "v"(sp + 4) : "memory");
                if (a.x != 0 && a.x == bb.x && a.y == bb.y) break;
            }
            k = ((u64)(u32)a.y << 32) | (u32)a.x;
            wx = __int_as_float(a.z);
            wy = __int_as_float(a.w);
            wz = __int_as_float(bb.z);
        }
        // reduce lanes 0-7 -> global winner; broadcast from lane 0
#pragma unroll
        for (int d1 = 4; d1 >= 1; d1 >>= 1) {
            u64 o = __shfl_xor(k, d1, 64);
            k = (o > k) ? o : k;
        }
        k = __shfl(k, 0, 64);              // all 64 lanes get the winner key
        const int g = (int)(0xFFFFFFFFu - (u32)(k & 0xFFFFFFFFull));
        const int jw = (g >> 13) & 7;      // owning block (CHUNK = 2^13)
        if (jw == j) {
            // winner is local: read coords from LDS (uniform addr: broadcast)
            const int lw = g - base;
            qx = P[lw * 3 + 0];
            qy = P[lw * 3 + 1];
            qz = P[lw * 3 + 2];
        } else {
            qx = __shfl(wx, jw, 64);       // lane jw polled the winning slot
            qy = __shfl(wy, jw, 64);
            qz = __shfl(wz, jw, 64);
        }
        if (wave == 0 && lane == 0) {
            sel_hist[s] = g;
            if (j == 0) out_idx[s] = (float)g;
        }
    }

    __syncthreads();
    if (j == 0) {
        const int gi = sel_hist[t];
        const float* __restrict__ p = pb + (size_t)gi * 3;
        out_pts[(size_t)t * 3 + 0] = p[0];
        out_pts[(size_t)t * 3 + 1] = p[1];
        out_pts[(size_t)t * 3 + 2] = p[2];
    }
}

// ---------------- fallback (no workspace): 1 block/batch --------------------
__global__ __launch_bounds__(NT) void fps_single(const float* __restrict__ pts,
                                                 float* __restrict__ out) {
#pragma clang fp contract(off)
    const int b = blockIdx.x;
    const int t = threadIdx.x;
    const float* __restrict__ pb = pts + (size_t)b * NP * 3;
    float* __restrict__ out_idx = out + (size_t)b * NS;
    float* __restrict__ out_pts = out + (size_t)NB * NS + (size_t)b * NS * 3;
    __shared__ int sel_hist[NS];
    __shared__ u64 cand[16];
    __shared__ int sel_sh;
    float md[NP / NT];
#pragma unroll
    for (int i = 0; i < NP / NT; ++i) md[i] = 1e10f;
    if (t == 0) { sel_hist[0] = 0; out_idx[0] = 0.0f; }
    float qx = pb[0], qy = pb[1], qz = pb[2];
    const int wave = t >> 6;
    const int lane = t & 63;
    for (int s = 1; s < NS; ++s) {
        float bestv = -1.0f;
        int besti = 0;
#pragma unroll
        for (int i = 0; i < NP / NT; ++i) {
            const int gi = t + i * NT;
            const float* __restrict__ p = pb + (size_t)gi * 3;
            float dx = p[0] - qx, dy = p[1] - qy, dz = p[2] - qz;
            float d = (dx * dx + dy * dy) + dz * dz;
            float nmd = fminf(md[i], d);
            md[i] = nmd;
            if (nmd > bestv) { bestv = nmd; besti = gi; }
        }
        u64 pk = ((u64)__float_as_uint(bestv) << 32) |
                 (u64)(0xFFFFFFFFu - (u32)besti);
#pragma unroll
        for (int m = 32; m >= 1; m >>= 1) {
            u64 o = __shfl_xor(pk, m, 64);
            pk = (o > pk) ? o : pk;
        }
        if (lane == 0) cand[wave] = pk;
        __syncthreads();
        if (wave == 0) {
            u64 c = (lane < 16) ? cand[lane] : 0ull;
#pragma unroll
            for (int m = 8; m >= 1; m >>= 1) {
                u64 o = __shfl_xor(c, m, 64);
                c = (o > c) ? o : c;
            }
            if (lane == 0) {
                int w = (int)(0xFFFFFFFFu - (u32)(c & 0xFFFFFFFFull));
                sel_sh = w; sel_hist[s] = w; out_idx[s] = (float)w;
            }
        }
        __syncthreads();
        const int sel = sel_sh;
        qx = pb[(size_t)sel * 3]; qy = pb[(size_t)sel * 3 + 1]; qz = pb[(size_t)sel * 3 + 2];
    }
    __syncthreads();
    {
        const int gi = sel_hist[t];
        const float* __restrict__ p = pb + (size_t)gi * 3;
        out_pts[(size_t)t * 3 + 0] = p[0];
        out_pts[(size_t)t * 3 + 1] = p[1];
        out_pts[(size_t)t * 3 + 2] = p[2];
    }
}

extern "C" void kernel_launch(void* const* d_in, const int* in_sizes, int n_in,
                              void* d_out, int out_size, void* d_ws, size_t ws_size,
                              hipStream_t stream) {
    const float* pts = (const float*)d_in[0];
    float* out = (float*)d_out;
    (void)in_sizes; (void)n_in; (void)out_size;

    const size_t v13_bytes = (size_t)NB * NS * BPB * 32;   // 8 MB
    if (ws_size >= v13_bytes) {
        u32* slots = (u32*)d_ws;
        hipMemsetAsync(d_ws, 0, v13_bytes, stream);
        void* args[] = {(void*)&pts, (void*)&out, (void*)&slots};
        hipLaunchCooperativeKernel((const void*)fps_v13, dim3(NB * BPB), dim3(NT),
                                   args, 0, stream);
    } else {
        hipLaunchKernelGGL(fps_single, dim3(NB), dim3(NT), 0, stream, pts, out);
    }
}

// Round 14
// 2228.963 us; speedup vs baseline: 1.2924x; 1.2924x over previous
//
#include <hip/hip_runtime.h>

#define NB 32
#define NP 65536
#define NS 1024
#define NT 1024
#define BPB 8                 // blocks per batch (proven best, R7)
#define CHUNK (NP / BPB)      // 8192 points per block
#define PPT (CHUNK / NT)      // 8 points per thread

typedef unsigned long long u64;
typedef unsigned int u32;
typedef int int4v __attribute__((ext_vector_type(4)));

// ---------------- R14: R7 + 2-deep pipelined slot polling -------------------
// Protocol = R7 verbatim (proven 2222us, absmax 0): per-s write-once 32B
// slots, h0={keylo,keyhi,x,y} h1={keylo,keyhi,z,0}, valid iff keylo!=0 &&
// h0.key==h1.key; all slot ops sc0 sc1 (bypass L1+L2 — R10/R11: cached poll
// lines are never invalidated by remote writes; R12: sc0sc1 polls are always
// LLC-served, "hot" slots don't exist; R13: only wave0 polls — extra pollers
// congest the LLC).
// New: the poll keeps TWO probes in flight (alternating register pairs) and
// checks the older with s_waitcnt vmcnt(2) while the newer flies -> slot
// sampling quantum ~RT/2 instead of RT; detect latency and inter-block skew
// band shrink. Each buffer is re-issued only after it was waited on (no
// write-to-pending-register hazard); loop contains no other VMEM ops so the
// vmcnt counts are exact; sched_barrier(0) after each wait (rule #18).
// CONTROL FLOW (R8/R9 deadlock rule): the slot store is straight-line
// lane-0 code that completes before any poll loop starts.
__global__ __launch_bounds__(NT) void fps_v14(const float* __restrict__ pts,
                                              float* __restrict__ out,
                                              u32* __restrict__ slots) {
#pragma clang fp contract(off)
    const int bid = blockIdx.x;
    const int b = bid >> 3;           // batch: consecutive bids (R7 mapping)
    const int j = bid & 7;
    const int t = threadIdx.x;
    const int wave = t >> 6;
    const int lane = t & 63;
    const int base = j * CHUNK;
    const float* __restrict__ pb = pts + (size_t)b * NP * 3;
    float* __restrict__ out_idx = out + (size_t)b * NS;
    float* __restrict__ out_pts = out + (size_t)NB * NS + (size_t)b * NS * 3;
    u32* __restrict__ slot_b = slots + (size_t)b * NS * BPB * 8;  // u32 words

    __shared__ float P[CHUNK * 3];    // 96 KB packed points
    __shared__ u64 cand[NT / 64];
    __shared__ int sel_hist[NS];
    __shared__ float qsh[3];

    // stage chunk into LDS, coalesced float4
    {
        const float4* __restrict__ src4 = (const float4*)(pb + (size_t)base * 3);
        float4* dst4 = (float4*)P;
#pragma unroll
        for (int k = 0; k < (CHUNK * 3 / 4) / NT; ++k) dst4[t + k * NT] = src4[t + k * NT];
    }
    if (t == 0) {
        sel_hist[0] = 0;
        if (j == 0) out_idx[0] = 0.0f;
        qsh[0] = pb[0]; qsh[1] = pb[1]; qsh[2] = pb[2];   // first sel = point 0
    }
    __syncthreads();

    // points -> registers, CONSECUTIVE range [t*8, t*8+8):
    // lowest lane == lowest global idx (exact ballot tie-break, R10-R13)
    float px[PPT], py[PPT], pz[PPT], md[PPT];
#pragma unroll
    for (int i = 0; i < PPT; ++i) {
        const int li = t * PPT + i;
        px[i] = P[li * 3 + 0];
        py[i] = P[li * 3 + 1];
        pz[i] = P[li * 3 + 2];
        md[i] = 1e10f;
    }
    float qx = qsh[0], qy = qsh[1], qz = qsh[2];

    for (int s = 1; s < NS; ++s) {
        float bv = -1.0f;
        int bi = 0;
#pragma unroll
        for (int i = 0; i < PPT; ++i) {
            float dx = px[i] - qx;
            float dy = py[i] - qy;
            float dz = pz[i] - qz;
            float d = (dx * dx + dy * dy) + dz * dz;   // match np reduce order
            float nmd = fminf(md[i], d);
            md[i] = nmd;
            if (nmd > bv) { bv = nmd; bi = t * PPT + i; }  // strict >: min idx
        }
        // wave argmax: f32 max reduce; ballot lowest lane among ties == min idx
        float m = bv;
#pragma unroll
        for (int d1 = 32; d1 >= 1; d1 >>= 1) m = fmaxf(m, __shfl_xor(m, d1, 64));
        u64 msk = __ballot(bv == m);
        int src = __ffsll((unsigned long long)msk) - 1;
        int biw = __shfl(bi, src, 64);
        if (lane == 0)
            cand[wave] = ((u64)__float_as_uint(m) << 32) |
                         (u64)(0xFFFFFFFFu - (u32)(base + biw));
        __syncthreads();
        if (wave == 0) {
            // stage-2: all lanes reduce the 16 wave candidates
            u64 c = cand[lane & 15];
#pragma unroll
            for (int d1 = 8; d1 >= 1; d1 >>= 1) {
                u64 o = __shfl_xor(c, d1, 64);
                c = (o > c) ? o : c;
            }
            // ---- writer: separate, loop-free, completes before polls ----
            const int g0 = (int)(0xFFFFFFFFu - (u32)(c & 0xFFFFFFFFull));
            float wx0 = 0.f, wy0 = 0.f, wz0 = 0.f;
            if (lane == 0) {
                const int lw = g0 - base;
                wx0 = P[lw * 3 + 0];
                wy0 = P[lw * 3 + 1];
                wz0 = P[lw * 3 + 2];
                int4v h0, h1;
                h0.x = (int)(u32)(c & 0xFFFFFFFFull);   // key lo = ~gidx != 0
                h0.y = (int)(u32)(c >> 32);             // key hi = valbits
                h0.z = __float_as_int(wx0);
                h0.w = __float_as_int(wy0);
                h1.x = h0.x;
                h1.y = h0.y;
                h1.z = __float_as_int(wz0);
                h1.w = 0;
                u32* sp = slot_b + ((size_t)s * BPB + j) * 8;
                asm volatile(
                    "global_store_dwordx4 %0, %2, off sc0 sc1\n\t"
                    "global_store_dwordx4 %1, %3, off sc0 sc1"
                    :: "v"(sp), "v"(sp + 4), "v"(h0), "v"(h1) : "memory");
            }
            // ---- pollers: 2-deep pipelined sc0sc1 probes ----
            if (lane < BPB) {
                u64 k = c;                        // lane j keeps own candidate
                float wx = 0.f, wy = 0.f, wz = 0.f;
                if (lane != j) {
                    const u32* sp = slot_b + ((size_t)s * BPB + lane) * 8;
                    int4v a0, b0, a1, b1;
                    // prologue: probe 0 in flight
                    asm volatile(
                        "global_load_dwordx4 %0, %2, off sc0 sc1\n\t"
                        "global_load_dwordx4 %1, %3, off sc0 sc1"
                        : "=v"(a0), "=v"(b0)
                        : "v"(sp), "v"(sp + 4) : "memory");
                    int use1 = 0;
                    for (;;) {
                        // keep a second probe in flight
                        asm volatile(
                            "global_load_dwordx4 %0, %2, off sc0 sc1\n\t"
                            "global_load_dwordx4 %1, %3, off sc0 sc1"
                            : "=v"(a1), "=v"(b1)
                            : "v"(sp), "v"(sp + 4) : "memory");
                        asm volatile("s_waitcnt vmcnt(2)" ::: "memory");
                        __builtin_amdgcn_sched_barrier(0);
                        if (a0.x != 0 && a0.x == b0.x && a0.y == b0.y) {
                            use1 = 0;
                            break;
                        }
                        asm volatile(
                            "global_load_dwordx4 %0, %2, off sc0 sc1\n\t"
                            "global_load_dwordx4 %1, %3, off sc0 sc1"
                            : "=v"(a0), "=v"(b0)
                            : "v"(sp), "v"(sp + 4) : "memory");
                        asm volatile("s_waitcnt vmcnt(2)" ::: "memory");
                        __builtin_amdgcn_sched_barrier(0);
                        if (a1.x != 0 && a1.x == b1.x && a1.y == b1.y) {
                            use1 = 1;
                            break;
                        }
                    }
                    // drain the still-flying probe before touching its regs
                    asm volatile("s_waitcnt vmcnt(0)" ::: "memory");
                    __builtin_amdgcn_sched_barrier(0);
                    int4v a = use1 ? a1 : a0;
                    int4v bb = use1 ? b1 : b0;
                    k = ((u64)(u32)a.y << 32) | (u32)a.x;
                    wx = __int_as_float(a.z);
                    wy = __int_as_float(a.w);
                    wz = __int_as_float(bb.z);
                }
                // reduce over the 8 participants (lanes 0-7)
#pragma unroll
                for (int d1 = 4; d1 >= 1; d1 >>= 1) {
                    u64 o = __shfl_xor(k, d1, 64);
                    k = (o > k) ? o : k;
                }
                const int g = (int)(0xFFFFFFFFu - (u32)(k & 0xFFFFFFFFull));
                const int jw = (g >> 13) & 7;      // owning block (CHUNK=2^13)
                float sx = __shfl(wx, jw, 64);
                float sy = __shfl(wy, jw, 64);
                float sz = __shfl(wz, jw, 64);
                if (lane == 0) {
                    sel_hist[s] = g;
                    if (jw == j) { qsh[0] = wx0; qsh[1] = wy0; qsh[2] = wz0; }
                    else         { qsh[0] = sx;  qsh[1] = sy;  qsh[2] = sz;  }
                    if (j == 0) out_idx[s] = (float)g;
                }
            }
        }
        __syncthreads();
        qx = qsh[0]; qy = qsh[1]; qz = qsh[2];
    }

    if (j == 0) {
        const int gi = sel_hist[t];
        const float* __restrict__ p = pb + (size_t)gi * 3;
        out_pts[(size_t)t * 3 + 0] = p[0];
        out_pts[(size_t)t * 3 + 1] = p[1];
        out_pts[(size_t)t * 3 + 2] = p[2];
    }
}

// ---------------- fallback (no workspace): 1 block/batch --------------------
__global__ __launch_bounds__(NT) void fps_single(const float* __restrict__ pts,
                                                 float* __restrict__ out) {
#pragma clang fp contract(off)
    const int b = blockIdx.x;
    const int t = threadIdx.x;
    const float* __restrict__ pb = pts + (size_t)b * NP * 3;
    float* __restrict__ out_idx = out + (size_t)b * NS;
    float* __restrict__ out_pts = out + (size_t)NB * NS + (size_t)b * NS * 3;
    __shared__ int sel_hist[NS];
    __shared__ u64 cand[16];
    __shared__ int sel_sh;
    float md[NP / NT];
#pragma unroll
    for (int i = 0; i < NP / NT; ++i) md[i] = 1e10f;
    if (t == 0) { sel_hist[0] = 0; out_idx[0] = 0.0f; }
    float qx = pb[0], qy = pb[1], qz = pb[2];
    const int wave = t >> 6;
    const int lane = t & 63;
    for (int s = 1; s < NS; ++s) {
        float bestv = -1.0f;
        int besti = 0;
#pragma unroll
        for (int i = 0; i < NP / NT; ++i) {
            const int gi = t + i * NT;
            const float* __restrict__ p = pb + (size_t)gi * 3;
            float dx = p[0] - qx, dy = p[1] - qy, dz = p[2] - qz;
            float d = (dx * dx + dy * dy) + dz * dz;
            float nmd = fminf(md[i], d);
            md[i] = nmd;
            if (nmd > bestv) { bestv = nmd; besti = gi; }
        }
        u64 pk = ((u64)__float_as_uint(bestv) << 32) |
                 (u64)(0xFFFFFFFFu - (u32)besti);
#pragma unroll
        for (int m = 32; m >= 1; m >>= 1) {
            u64 o = __shfl_xor(pk, m, 64);
            pk = (o > pk) ? o : pk;
        }
        if (lane == 0) cand[wave] = pk;
        __syncthreads();
        if (wave == 0) {
            u64 c = (lane < 16) ? cand[lane] : 0ull;
#pragma unroll
            for (int m = 8; m >= 1; m >>= 1) {
                u64 o = __shfl_xor(c, m, 64);
                c = (o > c) ? o : c;
            }
            if (lane == 0) {
                int w = (int)(0xFFFFFFFFu - (u32)(c & 0xFFFFFFFFull));
                sel_sh = w; sel_hist[s] = w; out_idx[s] = (float)w;
            }
        }
        __syncthreads();
        const int sel = sel_sh;
        qx = pb[(size_t)sel * 3]; qy = pb[(size_t)sel * 3 + 1]; qz = pb[(size_t)sel * 3 + 2];
    }
    __syncthreads();
    {
        const int gi = sel_hist[t];
        const float* __restrict__ p = pb + (size_t)gi * 3;
        out_pts[(size_t)t * 3 + 0] = p[0];
        out_pts[(size_t)t * 3 + 1] = p[1];
        out_pts[(size_t)t * 3 + 2] = p[2];
    }
}

extern "C" void kernel_launch(void* const* d_in, const int* in_sizes, int n_in,
                              void* d_out, int out_size, void* d_ws, size_t ws_size,
                              hipStream_t stream) {
    const float* pts = (const float*)d_in[0];
    float* out = (float*)d_out;
    (void)in_sizes; (void)n_in; (void)out_size;

    const size_t v14_bytes = (size_t)NB * NS * BPB * 32;   // 8 MB
    if (ws_size >= v14_bytes) {
        u32* slots = (u32*)d_ws;
        hipMemsetAsync(d_ws, 0, v14_bytes, stream);
        void* args[] = {(void*)&pts, (void*)&out, (void*)&slots};
        hipLaunchCooperativeKernel((const void*)fps_v14, dim3(NB * BPB), dim3(NT),
                                   args, 0, stream);
    } else {
        hipLaunchKernelGGL(fps_single, dim3(NB), dim3(NT), 0, stream, pts, out);
    }
}

// Round 15
// 2134.556 us; speedup vs baseline: 1.3495x; 1.0442x over previous
//
#include <hip/hip_runtime.h>

#define NB 32
#define NP 65536
#define NS 1024
#define NT 1024
#define BPB 8                 // blocks per batch (proven best, R7)
#define CHUNK (NP / BPB)      // 8192 points per block
#define PPT (CHUNK / NT)      // 8 points per thread

typedef unsigned long long u64;
typedef unsigned int u32;
typedef int int4v __attribute__((ext_vector_type(4)));
typedef float f2 __attribute__((ext_vector_type(2)));

// ---------------- R15: R7 protocol + packed-f32 (v_pk_*) inner loop ---------
// Exchange = R7 verbatim (proven 2222us floor across 7 variants): per-s
// write-once 32B slots, h0={keylo,keyhi,x,y} h1={keylo,keyhi,z,0}, valid iff
// keylo!=0 && h0.key==h1.key; all slot ops sc0 sc1 (R10-R12: cached polls go
// stale; LLC-served polls are latency-bound, hotness/pipelining don't help).
// New: inner loop on float2 ext-vectors -> v_pk_add/mul_f32 (2 pts/inst,
// bit-exact: two independent IEEE ops; fp contract(off) blocks pk_fma).
// Index recovery moved out of the loop: track bv only, post-ballot reverse
// scan picks lowest k with nm[k]==bv (same tie-break as in-loop strict->).
// CONTROL FLOW (R8/R9 rule): slot store is straight-line lane-0 code that
// completes before any poll loop starts.
__global__ __launch_bounds__(NT) void fps_v15(const float* __restrict__ pts,
                                              float* __restrict__ out,
                                              u32* __restrict__ slots) {
#pragma clang fp contract(off)
    const int bid = blockIdx.x;
    const int b = bid >> 3;           // batch: consecutive bids (R7 mapping)
    const int j = bid & 7;
    const int t = threadIdx.x;
    const int wave = t >> 6;
    const int lane = t & 63;
    const int base = j * CHUNK;
    const float* __restrict__ pb = pts + (size_t)b * NP * 3;
    float* __restrict__ out_idx = out + (size_t)b * NS;
    float* __restrict__ out_pts = out + (size_t)NB * NS + (size_t)b * NS * 3;
    u32* __restrict__ slot_b = slots + (size_t)b * NS * BPB * 8;  // u32 words

    __shared__ float P[CHUNK * 3];    // 96 KB packed points
    __shared__ u64 cand[NT / 64];
    __shared__ int sel_hist[NS];
    __shared__ float qsh[3];

    // stage chunk into LDS, coalesced float4
    {
        const float4* __restrict__ src4 = (const float4*)(pb + (size_t)base * 3);
        float4* dst4 = (float4*)P;
#pragma unroll
        for (int k = 0; k < (CHUNK * 3 / 4) / NT; ++k) dst4[t + k * NT] = src4[t + k * NT];
    }
    if (t == 0) {
        sel_hist[0] = 0;
        if (j == 0) out_idx[0] = 0.0f;
        qsh[0] = pb[0]; qsh[1] = pb[1]; qsh[2] = pb[2];   // first sel = point 0
    }
    __syncthreads();

    // points -> registers, CONSECUTIVE range [t*8, t*8+8), packed 2/reg:
    // lowest lane == lowest global idx (exact ballot tie-break, R10-R14)
    f2 PX[PPT / 2], PY[PPT / 2], PZ[PPT / 2], MD[PPT / 2];
#pragma unroll
    for (int i = 0; i < PPT / 2; ++i) {
        const int li = t * PPT + 2 * i;
        PX[i].x = P[li * 3 + 0];  PX[i].y = P[li * 3 + 3];
        PY[i].x = P[li * 3 + 1];  PY[i].y = P[li * 3 + 4];
        PZ[i].x = P[li * 3 + 2];  PZ[i].y = P[li * 3 + 5];
        MD[i] = (f2){1e10f, 1e10f};
    }
    float qx = qsh[0], qy = qsh[1], qz = qsh[2];

    for (int s = 1; s < NS; ++s) {
        const f2 q2x = {qx, qx}, q2y = {qy, qy}, q2z = {qz, qz};
        float nmv[PPT];
#pragma unroll
        for (int i = 0; i < PPT / 2; ++i) {
            f2 dx = PX[i] - q2x;              // v_pk_add_f32 (neg modifier)
            f2 dy = PY[i] - q2y;
            f2 dz = PZ[i] - q2z;
            f2 d = (dx * dx + dy * dy) + dz * dz;   // pk_mul/pk_add, np order
            f2 nm;
            nm.x = fminf(MD[i].x, d.x);
            nm.y = fminf(MD[i].y, d.y);
            MD[i] = nm;
            nmv[2 * i] = nm.x;
            nmv[2 * i + 1] = nm.y;
        }
        // per-thread max (tree; fmax pairs fuse to v_max3)
        float bv = fmaxf(fmaxf(fmaxf(nmv[0], nmv[1]), fmaxf(nmv[2], nmv[3])),
                         fmaxf(fmaxf(nmv[4], nmv[5]), fmaxf(nmv[6], nmv[7])));
        // wave argmax: f32 max reduce; ballot lowest lane among ties == min idx
        float m = bv;
#pragma unroll
        for (int d1 = 32; d1 >= 1; d1 >>= 1) m = fmaxf(m, __shfl_xor(m, d1, 64));
        u64 msk = __ballot(bv == m);
        int src = __ffsll((unsigned long long)msk) - 1;
        // lowest local k with nmv[k]==bv (reverse scan; == in-loop strict->)
        int kk = PPT - 1;
#pragma unroll
        for (int k2 = PPT - 2; k2 >= 0; --k2) kk = (nmv[k2] == bv) ? k2 : kk;
        int biw = __shfl(t * PPT + kk, src, 64);
        if (lane == 0)
            cand[wave] = ((u64)__float_as_uint(m) << 32) |
                         (u64)(0xFFFFFFFFu - (u32)(base + biw));
        __syncthreads();
        if (wave == 0) {
            // stage-2: all lanes reduce the 16 wave candidates
            u64 c = cand[lane & 15];
#pragma unroll
            for (int d1 = 8; d1 >= 1; d1 >>= 1) {
                u64 o = __shfl_xor(c, d1, 64);
                c = (o > c) ? o : c;
            }
            // ---- writer: separate, loop-free, completes before polls ----
            const int g0 = (int)(0xFFFFFFFFu - (u32)(c & 0xFFFFFFFFull));
            float wx0 = 0.f, wy0 = 0.f, wz0 = 0.f;
            if (lane == 0) {
                const int lw = g0 - base;
                wx0 = P[lw * 3 + 0];
                wy0 = P[lw * 3 + 1];
                wz0 = P[lw * 3 + 2];
                int4v h0, h1;
                h0.x = (int)(u32)(c & 0xFFFFFFFFull);   // key lo = ~gidx != 0
                h0.y = (int)(u32)(c >> 32);             // key hi = valbits
                h0.z = __float_as_int(wx0);
                h0.w = __float_as_int(wy0);
                h1.x = h0.x;
                h1.y = h0.y;
                h1.z = __float_as_int(wz0);
                h1.w = 0;
                u32* sp = slot_b + ((size_t)s * BPB + j) * 8;
                asm volatile(
                    "global_store_dwordx4 %0, %2, off sc0 sc1\n\t"
                    "global_store_dwordx4 %1, %3, off sc0 sc1"
                    :: "v"(sp), "v"(sp + 4), "v"(h0), "v"(h1) : "memory");
            }
            // ---- pollers: plain R7 sc0sc1 loop ----
            if (lane < BPB) {
                u64 k = c;                        // lane j keeps own candidate
                float wx = 0.f, wy = 0.f, wz = 0.f;
                if (lane != j) {
                    const u32* sp = slot_b + ((size_t)s * BPB + lane) * 8;
                    int4v a, bb;
                    for (;;) {
                        asm volatile(
                            "global_load_dwordx4 %0, %2, off sc0 sc1\n\t"
                            "global_load_dwordx4 %1, %3, off sc0 sc1\n\t"
                            "s_waitcnt vmcnt(0)"
                            : "=&v"(a), "=&v"(bb)
                            : "v"(sp), "v"(sp + 4) : "memory");
                        if (a.x != 0 && a.x == bb.x && a.y == bb.y) break;
                    }
                    k = ((u64)(u32)a.y << 32) | (u32)a.x;
                    wx = __int_as_float(a.z);
                    wy = __int_as_float(a.w);
                    wz = __int_as_float(bb.z);
                }
                // reduce over the 8 participants (lanes 0-7)
#pragma unroll
                for (int d1 = 4; d1 >= 1; d1 >>= 1) {
                    u64 o = __shfl_xor(k, d1, 64);
                    k = (o > k) ? o : k;
                }
                const int g = (int)(0xFFFFFFFFu - (u32)(k & 0xFFFFFFFFull));
                const int jw = (g >> 13) & 7;      // owning block (CHUNK=2^13)
                float sx = __shfl(wx, jw, 64);
                float sy = __shfl(wy, jw, 64);
                float sz = __shfl(wz, jw, 64);
                if (lane == 0) {
                    sel_hist[s] = g;
                    if (jw == j) { qsh[0] = wx0; qsh[1] = wy0; qsh[2] = wz0; }
                    else         { qsh[0] = sx;  qsh[1] = sy;  qsh[2] = sz;  }
                    if (j == 0) out_idx[s] = (float)g;
                }
            }
        }
        __syncthreads();
        qx = qsh[0]; qy = qsh[1]; qz = qsh[2];
    }

    if (j == 0) {
        const int gi = sel_hist[t];
        const float* __restrict__ p = pb + (size_t)gi * 3;
        out_pts[(size_t)t * 3 + 0] = p[0];
        out_pts[(size_t)t * 3 + 1] = p[1];
        out_pts[(size_t)t * 3 + 2] = p[2];
    }
}

// ---------------- fallback (no workspace): 1 block/batch --------------------
__global__ __launch_bounds__(NT) void fps_single(const float* __restrict__ pts,
                                                 float* __restrict__ out) {
#pragma clang fp contract(off)
    const int b = blockIdx.x;
    const int t = threadIdx.x;
    const float* __restrict__ pb = pts + (size_t)b * NP * 3;
    float* __restrict__ out_idx = out + (size_t)b * NS;
    float* __restrict__ out_pts = out + (size_t)NB * NS + (size_t)b * NS * 3;
    __shared__ int sel_hist[NS];
    __shared__ u64 cand[16];
    __shared__ int sel_sh;
    float md[NP / NT];
#pragma unroll
    for (int i = 0; i < NP / NT; ++i) md[i] = 1e10f;
    if (t == 0) { sel_hist[0] = 0; out_idx[0] = 0.0f; }
    float qx = pb[0], qy = pb[1], qz = pb[2];
    const int wave = t >> 6;
    const int lane = t & 63;
    for (int s = 1; s < NS; ++s) {
        float bestv = -1.0f;
        int besti = 0;
#pragma unroll
        for (int i = 0; i < NP / NT; ++i) {
            const int gi = t + i * NT;
            const float* __restrict__ p = pb + (size_t)gi * 3;
            float dx = p[0] - qx, dy = p[1] - qy, dz = p[2] - qz;
            float d = (dx * dx + dy * dy) + dz * dz;
            float nmd = fminf(md[i], d);
            md[i] = nmd;
            if (nmd > bestv) { bestv = nmd; besti = gi; }
        }
        u64 pk = ((u64)__float_as_uint(bestv) << 32) |
                 (u64)(0xFFFFFFFFu - (u32)besti);
#pragma unroll
        for (int m = 32; m >= 1; m >>= 1) {
            u64 o = __shfl_xor(pk, m, 64);
            pk = (o > pk) ? o : pk;
        }
        if (lane == 0) cand[wave] = pk;
        __syncthreads();
        if (wave == 0) {
            u64 c = (lane < 16) ? cand[lane] : 0ull;
#pragma unroll
            for (int m = 8; m >= 1; m >>= 1) {
                u64 o = __shfl_xor(c, m, 64);
                c = (o > c) ? o : c;
            }
            if (lane == 0) {
                int w = (int)(0xFFFFFFFFu - (u32)(c & 0xFFFFFFFFull));
                sel_sh = w; sel_hist[s] = w; out_idx[s] = (float)w;
            }
        }
        __syncthreads();
        const int sel = sel_sh;
        qx = pb[(size_t)sel * 3]; qy = pb[(size_t)sel * 3 + 1]; qz = pb[(size_t)sel * 3 + 2];
    }
    __syncthreads();
    {
        const int gi = sel_hist[t];
        const float* __restrict__ p = pb + (size_t)gi * 3;
        out_pts[(size_t)t * 3 + 0] = p[0];
        out_pts[(size_t)t * 3 + 1] = p[1];
        out_pts[(size_t)t * 3 + 2] = p[2];
    }
}

extern "C" void kernel_launch(void* const* d_in, const int* in_sizes, int n_in,
                              void* d_out, int out_size, void* d_ws, size_t ws_size,
                              hipStream_t stream) {
    const float* pts = (const float*)d_in[0];
    float* out = (float*)d_out;
    (void)in_sizes; (void)n_in; (void)out_size;

    const size_t v15_bytes = (size_t)NB * NS * BPB * 32;   // 8 MB
    if (ws_size >= v15_bytes) {
        u32* slots = (u32*)d_ws;
        hipMemsetAsync(d_ws, 0, v15_bytes, stream);
        void* args[] = {(void*)&pts, (void*)&out, (void*)&slots};
        hipLaunchCooperativeKernel((const void*)fps_v15, dim3(NB * BPB), dim3(NT),
                                   args, 0, stream);
    } else {
        hipLaunchKernelGGL(fps_single, dim3(NB), dim3(NT), 0, stream, pts, out);
    }
}